// Round 5
// baseline (941.174 us; speedup 1.0000x reference)
//
#include <hip/hip_runtime.h>
#include <hip/hip_bf16.h>

// Problem dims (compile-time)
#define BDIM 4
#define SDIM 2048
#define DDIM 1024
#define HDIM 16
#define FFDIM 4096
#define MROWS (BDIM*SDIM)   // 8192

using bf16 = __hip_bfloat16;
typedef __attribute__((ext_vector_type(8))) short short8;
typedef __attribute__((ext_vector_type(4))) float f32x4;

__device__ __forceinline__ f32x4 mfma16(short8 a, short8 b, f32x4 c) {
  return __builtin_amdgcn_mfma_f32_16x16x32_bf16(a, b, c, 0, 0, 0);
}

__device__ __forceinline__ void gll16(const void* g, void* l) {
  __builtin_amdgcn_global_load_lds((const __attribute__((address_space(1))) void*)g,
                                   (__attribute__((address_space(3))) void*)l, 16, 0, 0);
}

// ---------------------------------------------------------------------------
// GEMM: C[M,N] = A[M,K](bf16) * Bt[N,K]^T(bf16) + bias, epilogue variants.
// EPI 0: fp32 row-major out.  EPI 1: QKV scatter -> bf16 [3,B,H,S,64].
// EPI 2: exact GELU -> bf16 row-major out.
// 128x128 tile, BK=32, 256 threads (4 waves, 2x2), m97 structure.
// ---------------------------------------------------------------------------
template<int EPI>
__global__ __launch_bounds__(256)
void gemm_bt(const bf16* __restrict__ A, const bf16* __restrict__ Bt,
             const float* __restrict__ bias0, const float* __restrict__ bias1,
             const float* __restrict__ bias2,
             void* __restrict__ Cout, int K, int N)
{
  __shared__ bf16 As[128*32];
  __shared__ bf16 Bs[128*32];
  const int tid  = threadIdx.x;
  const int wave = tid >> 6;
  const int lane = tid & 63;
  const int llo  = lane & 15, lhi = lane >> 4;
  const int row0 = blockIdx.y * 128;
  const int col0 = blockIdx.x * 128;
  const int wm = wave >> 1, wn = wave & 1;

  f32x4 acc[4][4];
#pragma unroll
  for (int i = 0; i < 4; i++)
#pragma unroll
    for (int j = 0; j < 4; j++) acc[i][j] = (f32x4){0.f, 0.f, 0.f, 0.f};

  const int c0 = wave * 2, c1 = wave * 2 + 1;
  const size_t arow0 = (size_t)(row0 + c0*16 + (lane >> 2)) * K;
  const size_t arow1 = (size_t)(row0 + c1*16 + (lane >> 2)) * K;
  const size_t brow0 = (size_t)(col0 + c0*16 + (lane >> 2)) * K;
  const size_t brow1 = (size_t)(col0 + c1*16 + (lane >> 2)) * K;
  const int colb = (lane & 3) * 8;   // bf16 elems within 32-wide K tile

  const int nkt = K >> 5;
  for (int kt = 0; kt < nkt; ++kt) {
    __syncthreads();
    const int kofs = kt * 32 + colb;
    gll16(A  + arow0 + kofs, As + c0*512);
    gll16(A  + arow1 + kofs, As + c1*512);
    gll16(Bt + brow0 + kofs, Bs + c0*512);
    gll16(Bt + brow1 + kofs, Bs + c1*512);
    __syncthreads();
    short8 af[4], bfr[4];
#pragma unroll
    for (int mi = 0; mi < 4; mi++)
      af[mi] = *(const short8*)(As + (wm*64 + mi*16 + llo)*32 + lhi*8);
#pragma unroll
    for (int ni = 0; ni < 4; ni++)
      bfr[ni] = *(const short8*)(Bs + (wn*64 + ni*16 + llo)*32 + lhi*8);
#pragma unroll
    for (int mi = 0; mi < 4; mi++)
#pragma unroll
      for (int ni = 0; ni < 4; ni++)
        acc[mi][ni] = mfma16(af[mi], bfr[ni], acc[mi][ni]);
  }

#pragma unroll
  for (int mi = 0; mi < 4; mi++) {
#pragma unroll
    for (int ni = 0; ni < 4; ni++) {
      const int col = col0 + wn*64 + ni*16 + llo;
      float bv;
      if (EPI == 1) {
        const int which = col >> 10, win = col & 1023;
        const float* bp = (which == 0) ? bias0 : ((which == 1) ? bias1 : bias2);
        bv = bp[win];
      } else {
        bv = bias0[col];
      }
#pragma unroll
      for (int r = 0; r < 4; r++) {
        const int row = row0 + wm*64 + mi*16 + lhi*4 + r;
        float v = acc[mi][ni][r] + bv;
        if (EPI == 0) {
          ((float*)Cout)[(size_t)row * N + col] = v;
        } else if (EPI == 1) {
          const int which = col >> 10, win = col & 1023;
          const int h = win >> 6, dh = win & 63;
          const int b = row >> 11, s = row & 2047;
          ((bf16*)Cout)[((((size_t)which*BDIM + b)*HDIM + h)*SDIM + s)*64 + dh] =
              __float2bfloat16(v);
        } else {
          float gl = 0.5f * v * (1.f + erff(v * 0.70710678118654752f));
          ((bf16*)Cout)[(size_t)row * N + col] = __float2bfloat16(gl);
        }
      }
    }
  }
}

// ---------------------------------------------------------------------------
// Flash attention fwd. grid = (S/64, B*H), 256 threads (4 waves).
// Each wave owns 16 q-rows. KBLK=64. Online softmax in C-frag layout.
// ---------------------------------------------------------------------------
__global__ __launch_bounds__(256)
void attn_fwd(const bf16* __restrict__ qkv, const bf16* __restrict__ maskb,
              bf16* __restrict__ Obuf)
{
  __shared__ bf16 Ks[64*64];
  __shared__ bf16 Vt[64*64];   // transposed: Vt[dh][key]
  __shared__ bf16 Ms[64*64];   // mask bias tile [q][k]
  __shared__ bf16 Ps[4][16*64];

  const int tid  = threadIdx.x;
  const int wave = tid >> 6, lane = tid & 63;
  const int llo  = lane & 15, lhi = lane >> 4;
  const int bh = blockIdx.y;
  const int b = bh >> 4, h = bh & 15;
  const int q0 = blockIdx.x * 64;

  const bf16* Qp = qkv + (((size_t)0*BDIM + b)*HDIM + h) * (size_t)SDIM * 64;
  const bf16* Kp = qkv + (((size_t)1*BDIM + b)*HDIM + h) * (size_t)SDIM * 64;
  const bf16* Vp = qkv + (((size_t)2*BDIM + b)*HDIM + h) * (size_t)SDIM * 64;

  short8 qf[2];
  {
    const bf16* qrow = Qp + (size_t)(q0 + wave*16 + llo) * 64;
    qf[0] = *(const short8*)(qrow + lhi*8);
    qf[1] = *(const short8*)(qrow + 32 + lhi*8);
  }

  f32x4 o[4];
#pragma unroll
  for (int n = 0; n < 4; n++) o[n] = (f32x4){0.f, 0.f, 0.f, 0.f};
  float mrun[4], lrun[4];
#pragma unroll
  for (int r = 0; r < 4; r++) { mrun[r] = -INFINITY; lrun[r] = 0.f; }

  const int vrow = tid >> 2, vc0 = (tid & 3) * 16;
  const int c0 = wave * 2, c1 = wave * 2 + 1;

  for (int kt = 0; kt < SDIM/64; ++kt) {
    const int k0 = kt * 64;
    // V reg-stage (issue early; no LDS hazard)
    f32x4 vreg0 = *(const f32x4*)(Vp + (size_t)(k0 + vrow)*64 + vc0);
    f32x4 vreg1 = *(const f32x4*)(Vp + (size_t)(k0 + vrow)*64 + vc0 + 8);
    __syncthreads();
    // stage K tile + mask tile
    gll16(Kp + (size_t)(k0 + c0*8 + (lane >> 3))*64 + (lane & 7)*8, Ks + c0*512);
    gll16(Kp + (size_t)(k0 + c1*8 + (lane >> 3))*64 + (lane & 7)*8, Ks + c1*512);
    gll16(maskb + ((size_t)b*SDIM + q0 + c0*8 + (lane >> 3))*SDIM + k0 + (lane & 7)*8,
          Ms + c0*512);
    gll16(maskb + ((size_t)b*SDIM + q0 + c1*8 + (lane >> 3))*SDIM + k0 + (lane & 7)*8,
          Ms + c1*512);
    // write V transposed into LDS
    const bf16* v0 = (const bf16*)&vreg0;
    const bf16* v1 = (const bf16*)&vreg1;
#pragma unroll
    for (int j = 0; j < 8; j++) Vt[(vc0 + j)*64 + vrow] = v0[j];
#pragma unroll
    for (int j = 0; j < 8; j++) Vt[(vc0 + 8 + j)*64 + vrow] = v1[j];
    __syncthreads();

    // S = Q K^T  (16 q-rows x 64 keys per wave)
    float sv[4][4];
#pragma unroll
    for (int n = 0; n < 4; n++) {
      short8 kf0 = *(const short8*)(Ks + (n*16 + llo)*64 + lhi*8);
      short8 kf1 = *(const short8*)(Ks + (n*16 + llo)*64 + 32 + lhi*8);
      f32x4 z = (f32x4){0.f, 0.f, 0.f, 0.f};
      z = mfma16(qf[0], kf0, z);
      z = mfma16(qf[1], kf1, z);
#pragma unroll
      for (int r = 0; r < 4; r++)
        sv[n][r] = z[r]*0.125f +
            __bfloat162float(Ms[(wave*16 + lhi*4 + r)*64 + n*16 + llo]);
    }
    // online softmax
    float mnew[4], scale[4];
#pragma unroll
    for (int r = 0; r < 4; r++) {
      float rm = fmaxf(fmaxf(sv[0][r], sv[1][r]), fmaxf(sv[2][r], sv[3][r]));
      rm = fmaxf(rm, __shfl_xor(rm, 1));
      rm = fmaxf(rm, __shfl_xor(rm, 2));
      rm = fmaxf(rm, __shfl_xor(rm, 4));
      rm = fmaxf(rm, __shfl_xor(rm, 8));
      mnew[r] = fmaxf(mrun[r], rm);
      scale[r] = __expf(mrun[r] - mnew[r]);
      mrun[r] = mnew[r];
    }
    float rsum[4] = {0.f, 0.f, 0.f, 0.f};
#pragma unroll
    for (int n = 0; n < 4; n++)
#pragma unroll
      for (int r = 0; r < 4; r++) {
        float p = __expf(sv[n][r] - mnew[r]);
        sv[n][r] = p;
        rsum[r] += p;
      }
#pragma unroll
    for (int r = 0; r < 4; r++) {
      float rs = rsum[r];
      rs += __shfl_xor(rs, 1);
      rs += __shfl_xor(rs, 2);
      rs += __shfl_xor(rs, 4);
      rs += __shfl_xor(rs, 8);
      lrun[r] = lrun[r]*scale[r] + rs;
    }
#pragma unroll
    for (int n = 0; n < 4; n++)
#pragma unroll
      for (int r = 0; r < 4; r++) o[n][r] *= scale[r];
    // P -> LDS (C-layout -> A-layout round trip), per-wave private region
#pragma unroll
    for (int n = 0; n < 4; n++)
#pragma unroll
      for (int r = 0; r < 4; r++)
        Ps[wave][(lhi*4 + r)*64 + n*16 + llo] = __float2bfloat16(sv[n][r]);
    // PV
#pragma unroll
    for (int kk = 0; kk < 2; kk++) {
      short8 pf = *(const short8*)(&Ps[wave][llo*64 + kk*32 + lhi*8]);
#pragma unroll
      for (int n = 0; n < 4; n++) {
        short8 vf = *(const short8*)(Vt + (n*16 + llo)*64 + kk*32 + lhi*8);
        o[n] = mfma16(pf, vf, o[n]);
      }
    }
  }

#pragma unroll
  for (int n = 0; n < 4; n++)
#pragma unroll
    for (int r = 0; r < 4; r++) {
      float v = o[n][r] / lrun[r];
      const int row = q0 + wave*16 + lhi*4 + r;
      const int col = h*64 + n*16 + llo;
      Obuf[((size_t)b*SDIM + row)*DDIM + col] = __float2bfloat16(v);
    }
}

// ---------------------------------------------------------------------------
// out = resid + LayerNorm(y)*g + b ; optional bf16 copy of out.
// One block (256 thr) per row of 1024.
// ---------------------------------------------------------------------------
template<bool WB>
__global__ __launch_bounds__(256)
void add_ln(const float* __restrict__ resid, const float* __restrict__ y,
            const float* __restrict__ gam, const float* __restrict__ bet,
            float* __restrict__ outf, bf16* __restrict__ outb)
{
  __shared__ float red[4];
  const int row = blockIdx.x;
  const int t = threadIdx.x;
  float4 v = ((const float4*)(y + (size_t)row*DDIM))[t];
  float s = v.x + v.y + v.z + v.w;
#pragma unroll
  for (int off = 1; off < 64; off <<= 1) s += __shfl_xor(s, off);
  if ((t & 63) == 0) red[t >> 6] = s;
  __syncthreads();
  const float mean = (red[0]+red[1]+red[2]+red[3]) * (1.f/DDIM);
  const float dx = v.x-mean, dy = v.y-mean, dz = v.z-mean, dw = v.w-mean;
  float sq = dx*dx + dy*dy + dz*dz + dw*dw;
#pragma unroll
  for (int off = 1; off < 64; off <<= 1) sq += __shfl_xor(sq, off);
  __syncthreads();
  if ((t & 63) == 0) red[t >> 6] = sq;
  __syncthreads();
  const float var = (red[0]+red[1]+red[2]+red[3]) * (1.f/DDIM);
  const float rst = rsqrtf(var + 1e-6f);
  const float4 g  = ((const float4*)gam)[t];
  const float4 bb = ((const float4*)bet)[t];
  const float4 rv = ((const float4*)(resid + (size_t)row*DDIM))[t];
  float4 ov;
  ov.x = rv.x + dx*rst*g.x + bb.x;
  ov.y = rv.y + dy*rst*g.y + bb.y;
  ov.z = rv.z + dz*rst*g.z + bb.z;
  ov.w = rv.w + dw*rst*g.w + bb.w;
  ((float4*)(outf + (size_t)row*DDIM))[t] = ov;
  if (WB) {
    bf16* ob = outb + (size_t)row*DDIM + t*4;
    ob[0] = __float2bfloat16(ov.x);
    ob[1] = __float2bfloat16(ov.y);
    ob[2] = __float2bfloat16(ov.z);
    ob[3] = __float2bfloat16(ov.w);
  }
}

// ---------------------------------------------------------------------------
// Prep kernels
// ---------------------------------------------------------------------------
__global__ __launch_bounds__(256)
void transpose_cast(const float* __restrict__ in, bf16* __restrict__ out,
                    int R, int C)   // out[c][r] = in[r][c]; grid (C/32, R/32)
{
  __shared__ float tile[32][33];
  const int x = threadIdx.x & 31, y = threadIdx.x >> 5;
  const int c0 = blockIdx.x * 32, r0 = blockIdx.y * 32;
#pragma unroll
  for (int i = 0; i < 32; i += 8)
    tile[y + i][x] = in[(size_t)(r0 + y + i)*C + c0 + x];
  __syncthreads();
#pragma unroll
  for (int i = 0; i < 32; i += 8)
    out[(size_t)(c0 + y + i)*R + r0 + x] = __float2bfloat16(tile[x][y + i]);
}

__global__ __launch_bounds__(256)
void cast_to_bf16(const float* __restrict__ in, bf16* __restrict__ out, int n4)
{
  const int i = blockIdx.x * 256 + threadIdx.x;
  if (i < n4) {
    float4 v = ((const float4*)in)[i];
    bf16* o = out + (size_t)i*4;
    o[0] = __float2bfloat16(v.x);
    o[1] = __float2bfloat16(v.y);
    o[2] = __float2bfloat16(v.z);
    o[3] = __float2bfloat16(v.w);
  }
}

__global__ __launch_bounds__(256)
void mask_bias_kernel(const int* __restrict__ mask, bf16* __restrict__ bias, int n4)
{
  const int i = blockIdx.x * 256 + threadIdx.x;
  if (i < n4) {
    int4 m = ((const int4*)mask)[i];
    bf16* o = bias + (size_t)i*4;
    const bf16 neg = __float2bfloat16(-1e9f);
    const bf16 zer = __float2bfloat16(0.f);
    o[0] = (m.x == 0) ? neg : zer;
    o[1] = (m.y == 0) ? neg : zer;
    o[2] = (m.z == 0) ? neg : zer;
    o[3] = (m.w == 0) ? neg : zer;
  }
}

// ---------------------------------------------------------------------------
// Launch. Workspace layout (bytes), total 209,715,200 (~200 MB):
//   0         xb       16,777,216   [x1b aliases]
//   16777216  Wqkvt     6,291,456
//   23068672  Wot       2,097,152
//   25165824  W1t       8,388,608
//   33554432  W2t       8,388,608
//   41943040  maskb    33,554,432   [ff aliases]
//   75497472  qkv      50,331,648   [h1 aliases qkv+obuf]
//   125829120 obuf     16,777,216
//   142606336 aproj    33,554,432
//   176160768 x1f      33,554,432
// ---------------------------------------------------------------------------
extern "C" void kernel_launch(void* const* d_in, const int* in_sizes, int n_in,
                              void* d_out, int out_size, void* d_ws, size_t ws_size,
                              hipStream_t stream)
{
  (void)in_sizes; (void)n_in; (void)out_size; (void)ws_size;
  const float* x    = (const float*)d_in[0];
  const int*   mask = (const int*)d_in[1];
  const float* Wq   = (const float*)d_in[2];
  const float* bq   = (const float*)d_in[3];
  const float* Wk   = (const float*)d_in[4];
  const float* bk   = (const float*)d_in[5];
  const float* Wv   = (const float*)d_in[6];
  const float* bv   = (const float*)d_in[7];
  const float* Wo   = (const float*)d_in[8];
  const float* bo   = (const float*)d_in[9];
  const float* ln1g = (const float*)d_in[10];
  const float* ln1b = (const float*)d_in[11];
  const float* W1   = (const float*)d_in[12];
  const float* b1   = (const float*)d_in[13];
  const float* W2   = (const float*)d_in[14];
  const float* b2   = (const float*)d_in[15];
  const float* ln2g = (const float*)d_in[16];
  const float* ln2b = (const float*)d_in[17];
  float* out = (float*)d_out;

  char* ws = (char*)d_ws;
  bf16* xb    = (bf16*)(ws + 0);
  bf16* Wqkvt = (bf16*)(ws + 16777216);
  bf16* Wot   = (bf16*)(ws + 23068672);
  bf16* W1t   = (bf16*)(ws + 25165824);
  bf16* W2t   = (bf16*)(ws + 33554432);
  bf16* maskb = (bf16*)(ws + 41943040);
  bf16* qkv   = (bf16*)(ws + 75497472);
  bf16* obuf  = (bf16*)(ws + 125829120);
  float* aproj = (float*)(ws + 142606336);
  float* x1f   = (float*)(ws + 176160768);
  bf16* x1b = xb;            // alias (xb dead after QKV GEMM)
  bf16* h1  = qkv;           // alias over qkv+obuf (dead after O-proj)
  float* ffb = (float*)maskb;// alias (maskb dead after attention)

  cast_to_bf16<<<dim3(MROWS*DDIM/4/256), 256, 0, stream>>>(x, xb, MROWS*DDIM/4);
  transpose_cast<<<dim3(32, 32), 256, 0, stream>>>(Wq, Wqkvt, 1024, 1024);
  transpose_cast<<<dim3(32, 32), 256, 0, stream>>>(Wk, Wqkvt + 1024*1024, 1024, 1024);
  transpose_cast<<<dim3(32, 32), 256, 0, stream>>>(Wv, Wqkvt + 2*1024*1024, 1024, 1024);
  transpose_cast<<<dim3(32, 32), 256, 0, stream>>>(Wo, Wot, 1024, 1024);
  transpose_cast<<<dim3(FFDIM/32, 32), 256, 0, stream>>>(W1, W1t, 1024, FFDIM);
  transpose_cast<<<dim3(32, FFDIM/32), 256, 0, stream>>>(W2, W2t, FFDIM, 1024);
  mask_bias_kernel<<<dim3(BDIM*SDIM*SDIM/4/256), 256, 0, stream>>>(
      mask, maskb, BDIM*SDIM*SDIM/4);

  // QKV projection: [8192,1024] x [1024,3072]
  gemm_bt<1><<<dim3(3072/128, MROWS/128), 256, 0, stream>>>(
      xb, Wqkvt, bq, bk, bv, qkv, 1024, 3072);
  // attention
  attn_fwd<<<dim3(SDIM/64, BDIM*HDIM), 256, 0, stream>>>(qkv, maskb, obuf);
  // O projection -> fp32
  gemm_bt<0><<<dim3(1024/128, MROWS/128), 256, 0, stream>>>(
      obuf, Wot, bo, nullptr, nullptr, aproj, 1024, 1024);
  // x1 = x + LN(attn_out); also bf16 copy for FFN
  add_ln<true><<<dim3(MROWS), 256, 0, stream>>>(x, aproj, ln1g, ln1b, x1f, x1b);
  // FFN1 + GELU -> bf16
  gemm_bt<2><<<dim3(FFDIM/128, MROWS/128), 256, 0, stream>>>(
      x1b, W1t, b1, nullptr, nullptr, h1, 1024, FFDIM);
  // FFN2 -> fp32
  gemm_bt<0><<<dim3(1024/128, MROWS/128), 256, 0, stream>>>(
      h1, W2t, b2, nullptr, nullptr, ffb, FFDIM, 1024);
  // out = x1 + LN(ff)
  add_ln<false><<<dim3(MROWS), 256, 0, stream>>>(x1f, ffb, ln2g, ln2b, out, nullptr);
}

// Round 6
// 845.064 us; speedup vs baseline: 1.1137x; 1.1137x over previous
//
#include <hip/hip_runtime.h>
#include <hip/hip_bf16.h>

// Problem dims (compile-time)
#define BDIM 4
#define SDIM 2048
#define DDIM 1024
#define HDIM 16
#define FFDIM 4096
#define MROWS (BDIM*SDIM)   // 8192

using bf16 = __hip_bfloat16;
typedef __attribute__((ext_vector_type(8))) short short8;
typedef __attribute__((ext_vector_type(4))) short short4v;
typedef __attribute__((ext_vector_type(4))) float f32x4;

__device__ __forceinline__ f32x4 mfma16(short8 a, short8 b, f32x4 c) {
  return __builtin_amdgcn_mfma_f32_16x16x32_bf16(a, b, c, 0, 0, 0);
}

__device__ __forceinline__ void gll16(const void* g, void* l) {
  __builtin_amdgcn_global_load_lds((const __attribute__((address_space(1))) void*)g,
                                   (__attribute__((address_space(3))) void*)l, 16, 0, 0);
}

// ---------------------------------------------------------------------------
// GEMM: C[M,N] = A[M,K](bf16) * Bt[N,K]^T(bf16) + bias, epilogue variants.
// EPI 0: fp32 row-major out.  EPI 1: QKV scatter -> bf16 [3,B,H,S,64],
//        V slab written TRANSPOSED as [B,H,64,S] (short4 along s).
// EPI 2: exact GELU -> bf16 row-major out.
// 128x128 tile, BK=32, 256 threads (4 waves, 2x2), m97 structure.
// LDS XOR-swizzle (T2): element col16 C>>3 stored at slot (C>>3)^(row&3);
// staging pre-swizzles the GLOBAL source col (rule #21), LDS dest stays linear.
// ---------------------------------------------------------------------------
template<int EPI>
__global__ __launch_bounds__(256)
void gemm_bt(const bf16* __restrict__ A, const bf16* __restrict__ Bt,
             const float* __restrict__ bias0, const float* __restrict__ bias1,
             const float* __restrict__ bias2,
             void* __restrict__ Cout, int K, int N)
{
  __shared__ bf16 As[128*32];
  __shared__ bf16 Bs[128*32];
  const int tid  = threadIdx.x;
  const int wave = tid >> 6;
  const int lane = tid & 63;
  const int llo  = lane & 15, lhi = lane >> 4;
  const int row0 = blockIdx.y * 128;
  const int col0 = blockIdx.x * 128;
  const int wm = wave >> 1, wn = wave & 1;

  f32x4 acc[4][4];
#pragma unroll
  for (int i = 0; i < 4; i++)
#pragma unroll
    for (int j = 0; j < 4; j++) acc[i][j] = (f32x4){0.f, 0.f, 0.f, 0.f};

  const int c0 = wave * 2, c1 = wave * 2 + 1;
  const size_t arow0 = (size_t)(row0 + c0*16 + (lane >> 2)) * K;
  const size_t arow1 = (size_t)(row0 + c1*16 + (lane >> 2)) * K;
  const size_t brow0 = (size_t)(col0 + c0*16 + (lane >> 2)) * K;
  const size_t brow1 = (size_t)(col0 + c1*16 + (lane >> 2)) * K;
  // pre-swizzled source col: slot l&3 holds source col16 (l&3)^((l>>2)&3)
  const int colb = (((lane & 3) ^ ((lane >> 2) & 3))) * 8;
  const int rslot = (/*read*/ 0);
  (void)rslot;

  const int nkt = K >> 5;
  for (int kt = 0; kt < nkt; ++kt) {
    __syncthreads();
    const int kofs = kt * 32 + colb;
    gll16(A  + arow0 + kofs, As + c0*512);
    gll16(A  + arow1 + kofs, As + c1*512);
    gll16(Bt + brow0 + kofs, Bs + c0*512);
    gll16(Bt + brow1 + kofs, Bs + c1*512);
    __syncthreads();
    short8 af[4], bfr[4];
    const int rsw = ((lhi ^ (llo & 3)) * 8);   // swizzled read slot
#pragma unroll
    for (int mi = 0; mi < 4; mi++)
      af[mi] = *(const short8*)(As + (wm*64 + mi*16 + llo)*32 + rsw);
#pragma unroll
    for (int ni = 0; ni < 4; ni++)
      bfr[ni] = *(const short8*)(Bs + (wn*64 + ni*16 + llo)*32 + rsw);
#pragma unroll
    for (int mi = 0; mi < 4; mi++)
#pragma unroll
      for (int ni = 0; ni < 4; ni++)
        acc[mi][ni] = mfma16(af[mi], bfr[ni], acc[mi][ni]);
  }

#pragma unroll
  for (int mi = 0; mi < 4; mi++) {
#pragma unroll
    for (int ni = 0; ni < 4; ni++) {
      const int col = col0 + wn*64 + ni*16 + llo;
      float bv;
      if (EPI == 1) {
        const int which = col >> 10, win = col & 1023;
        const float* bp = (which == 0) ? bias0 : ((which == 1) ? bias1 : bias2);
        bv = bp[win];
      } else {
        bv = bias0[col];
      }
      if (EPI == 1) {
        const int which = col >> 10, win = col & 1023;
        const int h = win >> 6, dh = win & 63;
        if (which < 2) {
#pragma unroll
          for (int r = 0; r < 4; r++) {
            const int row = row0 + wm*64 + mi*16 + lhi*4 + r;
            const int b = row >> 11, s = row & 2047;
            float v = acc[mi][ni][r] + bv;
            ((bf16*)Cout)[((((size_t)which*BDIM + b)*HDIM + h)*SDIM + s)*64 + dh] =
                __float2bfloat16(v);
          }
        } else {
          // V slab -> transposed [B,H,64,S]; 4 consecutive s per lane
          const int row = row0 + wm*64 + mi*16 + lhi*4;
          const int b = row >> 11, s = row & 2047;
          short4v pk;
#pragma unroll
          for (int r = 0; r < 4; r++) {
            bf16 t = __float2bfloat16(acc[mi][ni][r] + bv);
            pk[r] = *(short*)&t;
          }
          bf16* vt = (bf16*)Cout + (size_t)2*BDIM*HDIM*SDIM*64;
          *(short4v*)(vt + (((size_t)b*HDIM + h)*64 + dh)*SDIM + s) = pk;
        }
      } else {
#pragma unroll
        for (int r = 0; r < 4; r++) {
          const int row = row0 + wm*64 + mi*16 + lhi*4 + r;
          float v = acc[mi][ni][r] + bv;
          if (EPI == 0) {
            ((float*)Cout)[(size_t)row * N + col] = v;
          } else {
            float gl = 0.5f * v * (1.f + erff(v * 0.70710678118654752f));
            ((bf16*)Cout)[(size_t)row * N + col] = __float2bfloat16(gl);
          }
        }
      }
    }
  }
}

// ---------------------------------------------------------------------------
// Flash attention fwd. grid = (S/64, B*H), 256 threads (4 waves).
// Each wave owns 16 q-rows. KBLK=64. Online softmax in C-frag layout.
// K and V^T staged via gll16 with pre-swizzled global source (T2);
// mask applied from packed bitmask (1 bit/key) in registers.
// ---------------------------------------------------------------------------
__global__ __launch_bounds__(256)
void attn_fwd(const bf16* __restrict__ qkv,
              const unsigned long long* __restrict__ mbits,
              bf16* __restrict__ Obuf)
{
  __shared__ bf16 Ks[64*64];      // [key][dh], swizzled slots
  __shared__ bf16 Vs[64*64];      // [dh][key], swizzled slots
  __shared__ bf16 Ps[4][16*64];   // per-wave P tile, swizzled slots

  const int tid  = threadIdx.x;
  const int wave = tid >> 6, lane = tid & 63;
  const int llo  = lane & 15, lhi = lane >> 4;
  const int bh = blockIdx.y;
  const int b = bh >> 4, h = bh & 15;
  const int q0 = blockIdx.x * 64;

  const bf16* Qp  = qkv + ((size_t)b*HDIM + h) * (size_t)SDIM * 64;
  const bf16* Kp  = qkv + ((size_t)(BDIM*HDIM) + b*HDIM + h) * (size_t)SDIM * 64;
  const bf16* Vtp = qkv + (size_t)2*BDIM*HDIM*SDIM*64
                        + ((size_t)b*HDIM + h) * (size_t)64 * SDIM;  // [64][S]

  short8 qf[2];
  {
    const bf16* qrow = Qp + (size_t)(q0 + wave*16 + llo) * 64;
    qf[0] = *(const short8*)(qrow + lhi*8);
    qf[1] = *(const short8*)(qrow + 32 + lhi*8);
  }

  f32x4 o[4];
#pragma unroll
  for (int n = 0; n < 4; n++) o[n] = (f32x4){0.f, 0.f, 0.f, 0.f};
  float mrun[4], lrun[4];
#pragma unroll
  for (int r = 0; r < 4; r++) { mrun[r] = -INFINITY; lrun[r] = 0.f; }

  const int c0 = wave * 2, c1 = wave * 2 + 1;
  const int srow = lane >> 3;                  // row within 8-row chunk
  const int scol = ((lane & 7) ^ srow) * 8;    // pre-swizzled source col (elems)
  const size_t mrow = ((size_t)b*SDIM + q0 + wave*16 + lhi*4) * 32;

  for (int kt = 0; kt < SDIM/64; ++kt) {
    const int k0 = kt * 64;
    __syncthreads();
    // stage K tile (rows=key, 128B) and V^T tile (rows=dh, stride S)
    gll16(Kp + (size_t)(k0 + c0*8 + srow)*64 + scol, Ks + c0*512);
    gll16(Kp + (size_t)(k0 + c1*8 + srow)*64 + scol, Ks + c1*512);
    gll16(Vtp + (size_t)(c0*8 + srow)*SDIM + k0 + scol, Vs + c0*512);
    gll16(Vtp + (size_t)(c1*8 + srow)*SDIM + k0 + scol, Vs + c1*512);
    // mask bits for this wave's 4 q-rows (broadcast across llo)
    unsigned long long mw[4];
#pragma unroll
    for (int r = 0; r < 4; r++) mw[r] = mbits[mrow + (size_t)r*32 + kt];
    __syncthreads();

    // S = Q K^T  (16 q-rows x 64 keys per wave)
    float sv[4][4];
#pragma unroll
    for (int n = 0; n < 4; n++) {
      const int krow = (n*16 + llo) * 64;
      const int sw   = llo & 7;
      short8 kf0 = *(const short8*)(Ks + krow + ((lhi ^ sw) * 8));
      short8 kf1 = *(const short8*)(Ks + krow + (((4 | lhi) ^ sw) * 8));
      f32x4 z = (f32x4){0.f, 0.f, 0.f, 0.f};
      z = mfma16(qf[0], kf0, z);
      z = mfma16(qf[1], kf1, z);
#pragma unroll
      for (int r = 0; r < 4; r++)
        sv[n][r] = z[r]*0.125f +
            (((mw[r] >> (n*16 + llo)) & 1ull) ? 0.f : -1e9f);
    }
    // online softmax
    float mnew[4], scale[4];
#pragma unroll
    for (int r = 0; r < 4; r++) {
      float rm = fmaxf(fmaxf(sv[0][r], sv[1][r]), fmaxf(sv[2][r], sv[3][r]));
      rm = fmaxf(rm, __shfl_xor(rm, 1));
      rm = fmaxf(rm, __shfl_xor(rm, 2));
      rm = fmaxf(rm, __shfl_xor(rm, 4));
      rm = fmaxf(rm, __shfl_xor(rm, 8));
      mnew[r] = fmaxf(mrun[r], rm);
      scale[r] = __expf(mrun[r] - mnew[r]);
      mrun[r] = mnew[r];
    }
    float rsum[4] = {0.f, 0.f, 0.f, 0.f};
#pragma unroll
    for (int n = 0; n < 4; n++)
#pragma unroll
      for (int r = 0; r < 4; r++) {
        float p = __expf(sv[n][r] - mnew[r]);
        sv[n][r] = p;
        rsum[r] += p;
      }
#pragma unroll
    for (int r = 0; r < 4; r++) {
      float rs = rsum[r];
      rs += __shfl_xor(rs, 1);
      rs += __shfl_xor(rs, 2);
      rs += __shfl_xor(rs, 4);
      rs += __shfl_xor(rs, 8);
      lrun[r] = lrun[r]*scale[r] + rs;
    }
#pragma unroll
    for (int n = 0; n < 4; n++)
#pragma unroll
      for (int r = 0; r < 4; r++) o[n][r] *= scale[r];
    // P -> LDS (C-layout -> A-layout), swizzled slots, per-wave region
#pragma unroll
    for (int n = 0; n < 4; n++)
#pragma unroll
      for (int r = 0; r < 4; r++) {
        const int prow = lhi*4 + r;
        const int slot = (n*2 + (llo >> 3)) ^ (prow & 7);
        Ps[wave][prow*64 + slot*8 + (llo & 7)] = __float2bfloat16(sv[n][r]);
      }
    // PV
#pragma unroll
    for (int kk = 0; kk < 2; kk++) {
      const int sl = ((kk*4 + lhi) ^ (llo & 7)) * 8;
      short8 pf = *(const short8*)(&Ps[wave][llo*64 + sl]);
#pragma unroll
      for (int n = 0; n < 4; n++) {
        short8 vf = *(const short8*)(Vs + (n*16 + llo)*64 + sl);
        o[n] = mfma16(pf, vf, o[n]);
      }
    }
  }

#pragma unroll
  for (int n = 0; n < 4; n++)
#pragma unroll
    for (int r = 0; r < 4; r++) {
      float v = o[n][r] / lrun[r];
      const int row = q0 + wave*16 + lhi*4 + r;
      const int col = h*64 + n*16 + llo;
      Obuf[((size_t)b*SDIM + row)*DDIM + col] = __float2bfloat16(v);
    }
}

// ---------------------------------------------------------------------------
// out = resid + LayerNorm(y)*g + b ; optional bf16 copy of out.
// One block (256 thr) per row of 1024.
// ---------------------------------------------------------------------------
template<bool WB>
__global__ __launch_bounds__(256)
void add_ln(const float* __restrict__ resid, const float* __restrict__ y,
            const float* __restrict__ gam, const float* __restrict__ bet,
            float* __restrict__ outf, bf16* __restrict__ outb)
{
  __shared__ float red[4];
  const int row = blockIdx.x;
  const int t = threadIdx.x;
  float4 v = ((const float4*)(y + (size_t)row*DDIM))[t];
  float s = v.x + v.y + v.z + v.w;
#pragma unroll
  for (int off = 1; off < 64; off <<= 1) s += __shfl_xor(s, off);
  if ((t & 63) == 0) red[t >> 6] = s;
  __syncthreads();
  const float mean = (red[0]+red[1]+red[2]+red[3]) * (1.f/DDIM);
  const float dx = v.x-mean, dy = v.y-mean, dz = v.z-mean, dw = v.w-mean;
  float sq = dx*dx + dy*dy + dz*dz + dw*dw;
#pragma unroll
  for (int off = 1; off < 64; off <<= 1) sq += __shfl_xor(sq, off);
  __syncthreads();
  if ((t & 63) == 0) red[t >> 6] = sq;
  __syncthreads();
  const float var = (red[0]+red[1]+red[2]+red[3]) * (1.f/DDIM);
  const float rst = rsqrtf(var + 1e-6f);
  const float4 g  = ((const float4*)gam)[t];
  const float4 bb = ((const float4*)bet)[t];
  const float4 rv = ((const float4*)(resid + (size_t)row*DDIM))[t];
  float4 ov;
  ov.x = rv.x + dx*rst*g.x + bb.x;
  ov.y = rv.y + dy*rst*g.y + bb.y;
  ov.z = rv.z + dz*rst*g.z + bb.z;
  ov.w = rv.w + dw*rst*g.w + bb.w;
  ((float4*)(outf + (size_t)row*DDIM))[t] = ov;
  if (WB) {
    bf16* ob = outb + (size_t)row*DDIM + t*4;
    ob[0] = __float2bfloat16(ov.x);
    ob[1] = __float2bfloat16(ov.y);
    ob[2] = __float2bfloat16(ov.z);
    ob[3] = __float2bfloat16(ov.w);
  }
}

// ---------------------------------------------------------------------------
// Prep kernels
// ---------------------------------------------------------------------------
__global__ __launch_bounds__(256)
void transpose_cast(const float* __restrict__ in, bf16* __restrict__ out,
                    int R, int C)   // out[c][r] = in[r][c]; grid (C/32, R/32)
{
  __shared__ float tile[32][33];
  const int x = threadIdx.x & 31, y = threadIdx.x >> 5;
  const int c0 = blockIdx.x * 32, r0 = blockIdx.y * 32;
#pragma unroll
  for (int i = 0; i < 32; i += 8)
    tile[y + i][x] = in[(size_t)(r0 + y + i)*C + c0 + x];
  __syncthreads();
#pragma unroll
  for (int i = 0; i < 32; i += 8)
    out[(size_t)(c0 + y + i)*R + r0 + x] = __float2bfloat16(tile[x][y + i]);
}

__global__ __launch_bounds__(256)
void cast_to_bf16(const float* __restrict__ in, bf16* __restrict__ out, int n4)
{
  const int i = blockIdx.x * 256 + threadIdx.x;
  if (i < n4) {
    float4 v = ((const float4*)in)[i];
    bf16* o = out + (size_t)i*4;
    o[0] = __float2bfloat16(v.x);
    o[1] = __float2bfloat16(v.y);
    o[2] = __float2bfloat16(v.z);
    o[3] = __float2bfloat16(v.w);
  }
}

// pack mask int32 -> 1 bit per entry; one wave per 64-entry word
__global__ __launch_bounds__(256)
void mask_bits_kernel(const int* __restrict__ mask,
                      unsigned long long* __restrict__ bits)
{
  const int wid = blockIdx.x * 4 + (threadIdx.x >> 6);
  const int lane = threadIdx.x & 63;
  const int m = mask[(size_t)wid * 64 + lane];
  const unsigned long long bal = __ballot(m != 0);
  if (lane == 0) bits[wid] = bal;
}

// ---------------------------------------------------------------------------
// Launch. Workspace layout (bytes), total 209,715,200 (~200 MB):
//   0         xb       16,777,216   [x1b aliases]
//   16777216  Wqkvt     6,291,456
//   23068672  Wot       2,097,152
//   25165824  W1t       8,388,608
//   33554432  W2t       8,388,608
//   41943040  mbits     2,097,152   [ffb (32MB) aliases 41943040..75497472]
//   75497472  qkv      50,331,648   [h1 aliases qkv+obuf; V slab = [B,H,64,S]]
//   125829120 obuf     16,777,216
//   142606336 aproj    33,554,432
//   176160768 x1f      33,554,432
// ---------------------------------------------------------------------------
extern "C" void kernel_launch(void* const* d_in, const int* in_sizes, int n_in,
                              void* d_out, int out_size, void* d_ws, size_t ws_size,
                              hipStream_t stream)
{
  (void)in_sizes; (void)n_in; (void)out_size; (void)ws_size;
  const float* x    = (const float*)d_in[0];
  const int*   mask = (const int*)d_in[1];
  const float* Wq   = (const float*)d_in[2];
  const float* bq   = (const float*)d_in[3];
  const float* Wk   = (const float*)d_in[4];
  const float* bk   = (const float*)d_in[5];
  const float* Wv   = (const float*)d_in[6];
  const float* bv   = (const float*)d_in[7];
  const float* Wo   = (const float*)d_in[8];
  const float* bo   = (const float*)d_in[9];
  const float* ln1g = (const float*)d_in[10];
  const float* ln1b = (const float*)d_in[11];
  const float* W1   = (const float*)d_in[12];
  const float* b1   = (const float*)d_in[13];
  const float* W2   = (const float*)d_in[14];
  const float* b2   = (const float*)d_in[15];
  const float* ln2g = (const float*)d_in[16];
  const float* ln2b = (const float*)d_in[17];
  float* out = (float*)d_out;

  char* ws = (char*)d_ws;
  bf16* xb    = (bf16*)(ws + 0);
  bf16* Wqkvt = (bf16*)(ws + 16777216);
  bf16* Wot   = (bf16*)(ws + 23068672);
  bf16* W1t   = (bf16*)(ws + 25165824);
  bf16* W2t   = (bf16*)(ws + 33554432);
  unsigned long long* mbits = (unsigned long long*)(ws + 41943040);
  bf16* qkv   = (bf16*)(ws + 75497472);
  bf16* obuf  = (bf16*)(ws + 125829120);
  float* aproj = (float*)(ws + 142606336);
  float* x1f   = (float*)(ws + 176160768);
  bf16* x1b = xb;             // alias (xb dead after QKV GEMM)
  bf16* h1  = qkv;            // alias over qkv+obuf (dead after O-proj)
  float* ffb = (float*)(ws + 41943040);  // alias over mbits (dead after attn)

  cast_to_bf16<<<dim3(MROWS*DDIM/4/256), 256, 0, stream>>>(x, xb, MROWS*DDIM/4);
  transpose_cast<<<dim3(32, 32), 256, 0, stream>>>(Wq, Wqkvt, 1024, 1024);
  transpose_cast<<<dim3(32, 32), 256, 0, stream>>>(Wk, Wqkvt + 1024*1024, 1024, 1024);
  transpose_cast<<<dim3(32, 32), 256, 0, stream>>>(Wv, Wqkvt + 2*1024*1024, 1024, 1024);
  transpose_cast<<<dim3(32, 32), 256, 0, stream>>>(Wo, Wot, 1024, 1024);
  transpose_cast<<<dim3(FFDIM/32, 32), 256, 0, stream>>>(W1, W1t, 1024, FFDIM);
  transpose_cast<<<dim3(32, FFDIM/32), 256, 0, stream>>>(W2, W2t, FFDIM, 1024);
  mask_bits_kernel<<<dim3(BDIM*SDIM*SDIM/64/4), 256, 0, stream>>>(mask, mbits);

  // QKV projection: [8192,1024] x [1024,3072]; V slab written transposed
  gemm_bt<1><<<dim3(3072/128, MROWS/128), 256, 0, stream>>>(
      xb, Wqkvt, bq, bk, bv, qkv, 1024, 3072);
  // attention
  attn_fwd<<<dim3(SDIM/64, BDIM*HDIM), 256, 0, stream>>>(qkv, mbits, obuf);
  // O projection -> fp32
  gemm_bt<0><<<dim3(1024/128, MROWS/128), 256, 0, stream>>>(
      obuf, Wot, bo, nullptr, nullptr, aproj, 1024, 1024);
  // x1 = x + LN(attn_out); also bf16 copy for FFN
  add_ln<true><<<dim3(MROWS), 256, 0, stream>>>(x, aproj, ln1g, ln1b, x1f, x1b);
  // FFN1 + GELU -> bf16
  gemm_bt<2><<<dim3(FFDIM/128, MROWS/128), 256, 0, stream>>>(
      x1b, W1t, b1, nullptr, nullptr, h1, 1024, FFDIM);
  // FFN2 -> fp32
  gemm_bt<0><<<dim3(1024/128, MROWS/128), 256, 0, stream>>>(
      h1, W2t, b2, nullptr, nullptr, ffb, FFDIM, 1024);
  // out = x1 + LN(ff)
  add_ln<false><<<dim3(MROWS), 256, 0, stream>>>(x1f, ffb, ln2g, ln2b, out, nullptr);
}